// Round 7
// baseline (164.541 us; speedup 1.0000x reference)
//
#include <hip/hip_runtime.h>
#include <hip/hip_cooperative_groups.h>

namespace cg = cooperative_groups;

// co_orbit[d,c] == (d != c)  =>
//   out[b,i,o,d] = sum_{j,k} Wd[sp[i,j]][o][k] * x[b,j,k,d]     (phase 3, K=1536)
//                + T[i*64+o][b]  (= sum_{j,k} W1[sp[i,j]][o][k]*S[b,j,k], phase 2)
//                + bias[o]
// Single COOPERATIVE kernel: phase1 (repack weight->Wfrag bf16 frag-order;
// x->BfragX/Sfrag frag-order)  -> grid.sync ->  phase2 (T-GEMM, 96 blocks)
// -> grid.sync -> phase3 (main GEMM, all 576 blocks).
// Fragment order: each 16(row)x32(k) subtile = 512 bf16 at lane*8+e,
// lane=(row&15)|(((k>>3)&3)<<4), e=k&7. K-loops are pure global_load+MFMA.

typedef short bf16x8 __attribute__((ext_vector_type(8)));
typedef float f32x4 __attribute__((ext_vector_type(4)));

static __device__ inline short f2bf(float f) {
    unsigned u = __builtin_bit_cast(unsigned, f);
    unsigned r = (u + 0x7fffu + ((u >> 16) & 1u)) >> 16;
    return (short)r;
}

#define MFMA16(a, b, c) __builtin_amdgcn_mfma_f32_16x16x32_bf16(a, b, c, 0, 0, 0)

__global__ __launch_bounds__(256, 3) void fused_kernel(
    const float* __restrict__ x, const float* __restrict__ weight,
    const float* __restrict__ bias, const int* __restrict__ sp,
    short* __restrict__ Wfrag, short* __restrict__ BfragX,
    short* __restrict__ Sfrag, float* __restrict__ Tt,
    float* __restrict__ out) {

    __shared__ __align__(16) float SMEM[10752];   // 43 KB: xs+Ss / Red
    cg::grid_group grid = cg::this_grid();

    const int t = threadIdx.x;
    const int bx = (int)blockIdx.x;
    const int lane = t & 63;
    const int w = t >> 6;

    // ---------------- phase 1: operand prep ----------------
    if (bx < 24) {
        const int s = bx;
        const int o = t >> 2;
        const int kq = (t & 3) << 4;
        #pragma unroll
        for (int h = 0; h < 2; ++h) {
            const int k0 = kq + h * 8;
            bf16x8 vd, v1;
            #pragma unroll
            for (int e = 0; e < 8; ++e) {
                const float2 wv = *(const float2*)(weight + ((size_t)((o * 64 + k0 + e) * 24 + s) << 1));
                vd[e] = f2bf(wv.x - wv.y);
                v1[e] = f2bf(wv.y);
            }
            const int lane_f = (o & 15) | (((k0 >> 3) & 3) << 4);
            const int sub = ((o >> 4) * 2 + (k0 >> 5)) * 512 + lane_f * 8;
            *(bf16x8*)&Wfrag[(size_t)s * 4096 + sub] = vd;          // p=0: Wd
            *(bf16x8*)&Wfrag[(size_t)(24 + s) * 4096 + sub] = v1;   // p=1: W1
        }
    } else if (bx < 88) {
        float* xs = SMEM;
        float* Ss = SMEM + 9216;
        const int b = bx - 24;
        const float4* xg = (const float4*)(x + (size_t)b * 9216);
        float4* x4 = (float4*)xs;
        #pragma unroll
        for (int u = 0; u < 9; ++u) x4[t + u * 256] = xg[t + u * 256];
        __syncthreads();
        #pragma unroll
        for (int u = 0; u < 6; ++u) {
            const int idx = t + u * 256;
            const float* p = xs + idx * 6;
            Ss[idx] = ((p[0] + p[1]) + (p[2] + p[3])) + (p[4] + p[5]);
        }
        __syncthreads();
        for (int cid = t; cid < 1344; cid += 256) {
            bf16x8 v;
            if (cid < 1152) {
                const int d = cid / 192;
                const int kk = (cid - d * 192) * 8;
                #pragma unroll
                for (int e = 0; e < 8; ++e) v[e] = f2bf(xs[(kk + e) * 6 + d]);
                const int n = b * 6 + d;
                const int lane_f = (n & 15) | (((kk >> 3) & 3) << 4);
                *(bf16x8*)&BfragX[(size_t)((n >> 4) * 48 + (kk >> 5)) * 512 + lane_f * 8] = v;
            } else {
                const int kk = (cid - 1152) * 8;
                #pragma unroll
                for (int e = 0; e < 8; ++e) v[e] = f2bf(Ss[kk + e]);
                const int lane_f = (b & 15) | (((kk >> 3) & 3) << 4);
                *(bf16x8*)&Sfrag[(size_t)((b >> 4) * 48 + (kk >> 5)) * 512 + lane_f * 8] = v;
            }
        }
    }

    grid.sync();

#define LOADSTEP(t_, buf, APTR, BB)                                              \
    {                                                                            \
        const short* ap = (APTR);                                                \
        const short* bp = (BB) + (t_) * 1024;                                    \
        _Pragma("unroll")                                                        \
        for (int f = 0; f < 4; ++f) {                                            \
            rA[buf][f] = *(const bf16x8*)(ap + f * 512);                         \
            rB[buf][f] = *(const bf16x8*)(bp + ((f >> 1) * 24576) + (f & 1) * 512); \
        }                                                                        \
    }

    // ---------------- phase 2: T[m][b] (stored Tt[b][m]), M=1536 N=64 K=1536 ----------------
    if (bx < 96) {
        float (*Red)[64][16] = (float (*)[64][16])SMEM;
        const int mt = bx % 48;
        const int bt = bx / 48;
        const int i  = mt >> 1;
        const int o0 = (mt & 1) * 32;
        const int n0 = bt * 32;
        const int jbase = w * 6;

        int sidx[6];
        #pragma unroll
        for (int t_ = 0; t_ < 6; ++t_) sidx[t_] = sp[i * 24 + jbase + t_];

        const size_t abase0 = (size_t)24 * 4096 + (size_t)(o0 >> 4) * 1024 + lane * 8;  // p=1
        const short* bbase = Sfrag + (size_t)(n0 >> 4) * 24576 + (size_t)jbase * 1024 + lane * 8;

        f32x4 acc[2][2] = {{{0.f,0.f,0.f,0.f},{0.f,0.f,0.f,0.f}},
                           {{0.f,0.f,0.f,0.f},{0.f,0.f,0.f,0.f}}};
        bf16x8 rA[2][4], rB[2][4];

        LOADSTEP(0, 0, Wfrag + (size_t)sidx[0] * 4096 + abase0, bbase)
        #pragma unroll
        for (int t_ = 0; t_ < 6; ++t_) {
            const int cur = t_ & 1;
            if (t_ < 5) LOADSTEP(t_ + 1, cur ^ 1, Wfrag + (size_t)sidx[t_ + 1] * 4096 + abase0, bbase)
            #pragma unroll
            for (int kc = 0; kc < 2; ++kc)
                #pragma unroll
                for (int mi = 0; mi < 2; ++mi)
                    #pragma unroll
                    for (int ni = 0; ni < 2; ++ni)
                        acc[mi][ni] = MFMA16(rA[cur][mi * 2 + kc], rB[cur][ni * 2 + kc], acc[mi][ni]);
        }

        #pragma unroll
        for (int mi = 0; mi < 2; ++mi)
            #pragma unroll
            for (int ni = 0; ni < 2; ++ni)
                *(f32x4*)&Red[w][lane][mi * 8 + ni * 4] = acc[mi][ni];
        __syncthreads();

        {
            const int l  = t & 63;
            const int g  = t >> 6;
            const int mi = g >> 1;
            const int ni = g & 1;
            const int fb = mi * 8 + ni * 4;
            f32x4 sum = *(const f32x4*)&Red[0][l][fb];
            #pragma unroll
            for (int ww = 1; ww < 4; ++ww) sum += *(const f32x4*)&Red[ww][l][fb];

            const int bcol = n0 + ni * 16 + (l & 15);
            const int rb = (l >> 4) * 4;
            const int mbase = i * 64 + o0 + mi * 16 + rb;
            *(f32x4*)&Tt[(size_t)bcol * 1536 + mbase] = sum;   // transposed store
        }
    }

    grid.sync();

    // ---------------- phase 3: main GEMM  M=1536 N=384 K=1536 ----------------
    {
        float (*Red)[64][16] = (float (*)[64][16])SMEM;
        const int mt = bx % 48;
        const int nt = bx / 48;          // 0..11
        const int i  = mt >> 1;
        const int o0 = (mt & 1) * 32;
        const int n0 = nt * 32;
        const int jbase = w * 6;

        int sidx[6];
        #pragma unroll
        for (int t_ = 0; t_ < 6; ++t_) sidx[t_] = sp[i * 24 + jbase + t_];

        const size_t abase0 = (size_t)(o0 >> 4) * 1024 + lane * 8;               // p=0
        const short* bbase = BfragX + (size_t)(n0 >> 4) * 24576 + (size_t)jbase * 1024 + lane * 8;

        f32x4 acc[2][2] = {{{0.f,0.f,0.f,0.f},{0.f,0.f,0.f,0.f}},
                           {{0.f,0.f,0.f,0.f},{0.f,0.f,0.f,0.f}}};
        bf16x8 rA[2][4], rB[2][4];

        LOADSTEP(0, 0, Wfrag + (size_t)sidx[0] * 4096 + abase0, bbase)
        #pragma unroll
        for (int t_ = 0; t_ < 6; ++t_) {
            const int cur = t_ & 1;
            if (t_ < 5) LOADSTEP(t_ + 1, cur ^ 1, Wfrag + (size_t)sidx[t_ + 1] * 4096 + abase0, bbase)
            #pragma unroll
            for (int kc = 0; kc < 2; ++kc)
                #pragma unroll
                for (int mi = 0; mi < 2; ++mi)
                    #pragma unroll
                    for (int ni = 0; ni < 2; ++ni)
                        acc[mi][ni] = MFMA16(rA[cur][mi * 2 + kc], rB[cur][ni * 2 + kc], acc[mi][ni]);
        }

        #pragma unroll
        for (int mi = 0; mi < 2; ++mi)
            #pragma unroll
            for (int ni = 0; ni < 2; ++ni)
                *(f32x4*)&Red[w][lane][mi * 8 + ni * 4] = acc[mi][ni];
        __syncthreads();

        {
            const int l  = t & 63;
            const int g  = t >> 6;
            const int mi = g >> 1;
            const int ni = g & 1;
            const int fb = mi * 8 + ni * 4;
            f32x4 sum = *(const f32x4*)&Red[0][l][fb];
            #pragma unroll
            for (int ww = 1; ww < 4; ++ww) sum += *(const f32x4*)&Red[ww][l][fb];

            // C/D layout: col = lane&15, row = (lane>>4)*4 + r  [verified r2-r6]
            const int col = n0 + ni * 16 + (l & 15);
            const int b = col / 6;
            const int d = col - b * 6;
            const int rb = (l >> 4) * 4;
            const int obase = o0 + mi * 16 + rb;
            const int mbase = i * 64 + obase;
            const f32x4 tv = *(const f32x4*)&Tt[(size_t)b * 1536 + mbase];
            const f32x4 bv = *(const f32x4*)&bias[obase];
            #pragma unroll
            for (int r = 0; r < 4; ++r) {
                out[((size_t)(b * 24 + i)) * 384 + (obase + r) * 6 + d] = sum[r] + tv[r] + bv[r];
            }
        }
    }
}

extern "C" void kernel_launch(void* const* d_in, const int* in_sizes, int n_in,
                              void* d_out, int out_size, void* d_ws, size_t ws_size,
                              hipStream_t stream) {
    const float* x      = (const float*)d_in[0];
    const float* weight = (const float*)d_in[1];
    const float* bias   = (const float*)d_in[2];
    const int*   sp     = (const int*)d_in[3];
    // d_in[4] = co_orbit: folded into the (d != c) factorization.

    short* Wfrag  = (short*)d_ws;                     // 2*24*4096 = 196608 bf16
    short* BfragX = Wfrag + 196608;                   // 384*1536  = 589824 bf16
    short* Sfrag  = BfragX + 589824;                  // 64*1536   =  98304 bf16
    float* Tt     = (float*)(Sfrag + 98304);          // 64*1536   =  98304 f32 (Tt[b][m])
    float* outp   = (float*)d_out;

    void* args[] = {(void*)&x, (void*)&weight, (void*)&bias, (void*)&sp,
                    (void*)&Wfrag, (void*)&BfragX, (void*)&Sfrag, (void*)&Tt,
                    (void*)&outp};
    hipLaunchCooperativeKernel((const void*)fused_kernel, dim3(576), dim3(256),
                               args, 0, stream);
}

// Round 8
// 22.954 us; speedup vs baseline: 7.1684x; 7.1684x over previous
//
#include <hip/hip_runtime.h>

// co_orbit[d,c] == (d != c)  =>
//   out[b,i,o,d] = sum_{j,k} Wd[sp[i,j]][o][k] * x[b,j,k,d]     (main, K=1536)
//                + sum_{j,k} W1[sp[i,j]][o][k] * S[b,j,k]        (T-term)
//                + bias[o]
// Two kernels: prep (repack weight -> Wfrag{Wd,W1}; x -> BfragX, S -> Sfrag,
// all in MFMA fragment order), then ONE fused GEMM: each 32x32 output block
// also computes its own 32m x 16b T-tile (its n-range spans exactly one
// 16-b group: 96 cols = 16 b => bg = nt/3) from W1 panels + Sfrag.
// Fragment order: each 16(row)x32(k) subtile = 512 bf16 at lane*8+e,
// lane=(row&15)|(((k>>3)&3)<<4), e=k&7. K-loops: pure global_load+MFMA,
// no LDS/barriers; LDS only for the 4-wave split-K reduction.

typedef short bf16x8 __attribute__((ext_vector_type(8)));
typedef float f32x4 __attribute__((ext_vector_type(4)));

static __device__ inline short f2bf(float f) {
    unsigned u = __builtin_bit_cast(unsigned, f);
    unsigned r = (u + 0x7fffu + ((u >> 16) & 1u)) >> 16;
    return (short)r;
}

#define MFMA16(a, b, c) __builtin_amdgcn_mfma_f32_16x16x32_bf16(a, b, c, 0, 0, 0)

// ---------------- prep: blocks 0..23 weight repack, 24..87 B/S build ----------------
__global__ __launch_bounds__(512) void prep_kernel(const float* __restrict__ weight,
                                                   const float* __restrict__ x,
                                                   short* __restrict__ Wfrag,
                                                   short* __restrict__ BfragX,
                                                   short* __restrict__ Sfrag) {
    __shared__ float xs[9216];
    __shared__ float Ss[1536];
    const int t = threadIdx.x;
    const int blk = blockIdx.x;

    if (blk < 24) {
        const int s = blk;
        const int o = t >> 3;             // 0..63
        const int k0 = (t & 7) << 3;      // one 8-chunk
        bf16x8 vd, v1;
        #pragma unroll
        for (int e = 0; e < 8; ++e) {
            const float2 wv = *(const float2*)(weight + ((size_t)((o * 64 + k0 + e) * 24 + s) << 1));
            vd[e] = f2bf(wv.x - wv.y);
            v1[e] = f2bf(wv.y);
        }
        const int lane_f = (o & 15) | (((k0 >> 3) & 3) << 4);
        const int sub = ((o >> 4) * 2 + (k0 >> 5)) * 512 + lane_f * 8;
        *(bf16x8*)&Wfrag[(size_t)s * 4096 + sub] = vd;          // p=0: Wd
        *(bf16x8*)&Wfrag[(size_t)(24 + s) * 4096 + sub] = v1;   // p=1: W1
    } else {
        const int b = blk - 24;
        const float4* xg = (const float4*)(x + (size_t)b * 9216);
        float4* x4 = (float4*)xs;
        for (int idx = t; idx < 2304; idx += 512) x4[idx] = xg[idx];
        __syncthreads();
        #pragma unroll
        for (int u = 0; u < 3; ++u) {
            const int idx = t + u * 512;
            const float* p = xs + idx * 6;
            Ss[idx] = ((p[0] + p[1]) + (p[2] + p[3])) + (p[4] + p[5]);
        }
        __syncthreads();
        // 1152 x-chunks (6 d-rows x 192) + 192 S-chunks
        for (int cid = t; cid < 1344; cid += 512) {
            if (cid < 1152) {
                const int d = cid / 192;
                const int kk = (cid - d * 192) * 8;
                bf16x8 v;
                #pragma unroll
                for (int e = 0; e < 8; ++e) v[e] = f2bf(xs[(kk + e) * 6 + d]);
                const int n = b * 6 + d;
                const int lane_f = (n & 15) | (((kk >> 3) & 3) << 4);
                *(bf16x8*)&BfragX[(size_t)((n >> 4) * 48 + (kk >> 5)) * 512 + lane_f * 8] = v;
            } else {
                const int kk = (cid - 1152) * 8;
                bf16x8 v;
                #pragma unroll
                for (int e = 0; e < 8; ++e) v[e] = f2bf(Ss[kk + e]);
                const int lane_f = (b & 15) | (((kk >> 3) & 3) << 4);
                *(bf16x8*)&Sfrag[(size_t)((b >> 4) * 48 + (kk >> 5)) * 512 + lane_f * 8] = v;
            }
        }
    }
}

// ------- fused GEMM: main (M=1536 N=384 K=1536) + per-block T (32m x 16b) -------
__global__ __launch_bounds__(256, 3) void gemm_kernel(const short* __restrict__ Wfrag,
                                                      const short* __restrict__ BfragX,
                                                      const short* __restrict__ Sfrag,
                                                      const float* __restrict__ bias,
                                                      const int* __restrict__ sp,
                                                      float* __restrict__ out) {
    __shared__ __align__(16) float RedM[4][64][16];   // 16 KB
    __shared__ __align__(16) float RedT[4][64][8];    //  8 KB

    const int tid = threadIdx.x;
    const int lane = tid & 63;
    const int w = tid >> 6;          // 0..3

    const int bx = (int)blockIdx.x;
    const int mt = bx % 48;
    const int nt = bx / 48;          // 0..11
    const int i  = mt >> 1;
    const int o0 = (mt & 1) * 32;
    const int n0 = nt * 32;
    const int bg = nt / 3;           // the single 16-b group this n-range touches

    const int jbase = w * 6;         // 4 waves x 6 j = 24
    int sidx[6];
    #pragma unroll
    for (int t_ = 0; t_ < 6; ++t_) sidx[t_] = sp[i * 24 + jbase + t_];

    const size_t abase0  = (size_t)(o0 >> 4) * 1024 + lane * 8;              // p=0 (Wd)
    const size_t a1base0 = (size_t)24 * 4096 + abase0;                       // p=1 (W1)
    const short* bbase = BfragX + (size_t)(n0 >> 4) * 24576 + (size_t)jbase * 1024 + lane * 8;
    const short* sbase = Sfrag  + (size_t)bg * 24576 + (size_t)jbase * 1024 + lane * 8;

    f32x4 acc[2][2] = {{{0.f,0.f,0.f,0.f},{0.f,0.f,0.f,0.f}},
                       {{0.f,0.f,0.f,0.f},{0.f,0.f,0.f,0.f}}};
    f32x4 accT[2] = {{0.f,0.f,0.f,0.f},{0.f,0.f,0.f,0.f}};
    bf16x8 rA[2][4], rB[2][4];

#define LOADSTEP(t_, buf)                                                       \
    {                                                                           \
        const short* ap = Wfrag + (size_t)sidx[t_] * 4096 + abase0;             \
        const short* bp = bbase + (t_) * 1024;                                  \
        _Pragma("unroll")                                                       \
        for (int f = 0; f < 4; ++f) {                                           \
            rA[buf][f] = *(const bf16x8*)(ap + f * 512);                        \
            rB[buf][f] = *(const bf16x8*)(bp + ((f >> 1) * 24576) + (f & 1) * 512); \
        }                                                                       \
    }

    LOADSTEP(0, 0)
    #pragma unroll
    for (int t_ = 0; t_ < 6; ++t_) {
        const int cur = t_ & 1;
        if (t_ < 5) LOADSTEP(t_ + 1, cur ^ 1)

        // T-term operands for this step (not double-buffered; hides under main MFMAs)
        bf16x8 rA1[4], rBs[2];
        {
            const short* a1p = Wfrag + (size_t)sidx[t_] * 4096 + a1base0;
            const short* spp = sbase + t_ * 1024;
            #pragma unroll
            for (int f = 0; f < 4; ++f) rA1[f] = *(const bf16x8*)(a1p + f * 512);
            rBs[0] = *(const bf16x8*)spp;
            rBs[1] = *(const bf16x8*)(spp + 512);
        }

        #pragma unroll
        for (int kc = 0; kc < 2; ++kc)
            #pragma unroll
            for (int mi = 0; mi < 2; ++mi)
                #pragma unroll
                for (int ni = 0; ni < 2; ++ni)
                    acc[mi][ni] = MFMA16(rA[cur][mi * 2 + kc], rB[cur][ni * 2 + kc], acc[mi][ni]);

        #pragma unroll
        for (int kc = 0; kc < 2; ++kc)
            #pragma unroll
            for (int mi = 0; mi < 2; ++mi)
                accT[mi] = MFMA16(rA1[mi * 2 + kc], rBs[kc], accT[mi]);
    }
#undef LOADSTEP

    #pragma unroll
    for (int mi = 0; mi < 2; ++mi) {
        #pragma unroll
        for (int ni = 0; ni < 2; ++ni)
            *(f32x4*)&RedM[w][lane][mi * 8 + ni * 4] = acc[mi][ni];
        *(f32x4*)&RedT[w][lane][mi * 4] = accT[mi];
    }
    __syncthreads();

    {
        const int l  = tid & 63;
        const int g  = tid >> 6;
        const int mi = g >> 1;
        const int ni = g & 1;
        const int fb = mi * 8 + ni * 4;
        f32x4 sum = *(const f32x4*)&RedM[0][l][fb];
        #pragma unroll
        for (int ww = 1; ww < 4; ++ww) sum += *(const f32x4*)&RedM[ww][l][fb];

        // C/D layout: col = lane&15, row = (lane>>4)*4 + r  [verified r2-r6]
        const int col = n0 + ni * 16 + (l & 15);
        const int b = col / 6;
        const int d = col - b * 6;
        const int bcol = b - bg * 16;              // 0..15 within this block's b-group
        const int lT = ((l >> 4) << 4) | bcol;     // lane holding (same row group, col=bcol)
        f32x4 ts = *(const f32x4*)&RedT[0][lT][mi * 4];
        #pragma unroll
        for (int ww = 1; ww < 4; ++ww) ts += *(const f32x4*)&RedT[ww][lT][mi * 4];

        const int rb = (l >> 4) * 4;
        const int obase = o0 + mi * 16 + rb;
        const f32x4 bv = *(const f32x4*)&bias[obase];
        #pragma unroll
        for (int r = 0; r < 4; ++r) {
            out[((size_t)(b * 24 + i)) * 384 + (obase + r) * 6 + d] = sum[r] + ts[r] + bv[r];
        }
    }
}

extern "C" void kernel_launch(void* const* d_in, const int* in_sizes, int n_in,
                              void* d_out, int out_size, void* d_ws, size_t ws_size,
                              hipStream_t stream) {
    const float* x      = (const float*)d_in[0];
    const float* weight = (const float*)d_in[1];
    const float* bias   = (const float*)d_in[2];
    const int*   sp     = (const int*)d_in[3];
    // d_in[4] = co_orbit: folded into the (d != c) factorization.

    short* Wfrag  = (short*)d_ws;                     // 2*24*4096 = 196608 bf16
    short* BfragX = Wfrag + 196608;                   // 384*1536  = 589824 bf16
    short* Sfrag  = BfragX + 589824;                  // 64*1536   =  98304 bf16

    prep_kernel<<<88, 512, 0, stream>>>(weight, x, Wfrag, BfragX, Sfrag);
    gemm_kernel<<<576, 256, 0, stream>>>(Wfrag, BfragX, Sfrag, bias, sp, (float*)d_out);
}

// Round 9
// 22.517 us; speedup vs baseline: 7.3073x; 1.0194x over previous
//
#include <hip/hip_runtime.h>

// co_orbit[d,c] == (d != c)  =>
//   out[b,i,o,d] = sum_{j,k} Wd[sp[i,j]][o][k] * x[b,j,k,d]     (main, K=1536)
//                + sum_{j,k} W1[sp[i,j]][o][k] * S[b,j,k]        (T-term)
//                + bias[o]
// Two kernels: prep (repack weight -> Wfrag{Wd,W1}; x -> BfragX, S -> Sfrag,
// all in MFMA fragment order), then ONE fused GEMM: each 32x32 output block
// also computes its own 32m x 16b T-tile (bg = nt/3) from W1 panels + Sfrag.
// Fragment order: each 16(row)x32(k) subtile = 512 bf16 at lane*8+e,
// lane=(row&15)|(((k>>3)&3)<<4), e=k&7. K-loops: pure global_load+MFMA,
// ALL operands (main + T) double-buffered one step ahead; LDS only for the
// 4-wave split-K reduction.

typedef short bf16x8 __attribute__((ext_vector_type(8)));
typedef float f32x4 __attribute__((ext_vector_type(4)));

static __device__ inline short f2bf(float f) {
    unsigned u = __builtin_bit_cast(unsigned, f);
    unsigned r = (u + 0x7fffu + ((u >> 16) & 1u)) >> 16;
    return (short)r;
}

#define MFMA16(a, b, c) __builtin_amdgcn_mfma_f32_16x16x32_bf16(a, b, c, 0, 0, 0)

// ---------------- prep: blocks 0..23 weight repack, 24..87 B/S build ----------------
__global__ __launch_bounds__(512) void prep_kernel(const float* __restrict__ weight,
                                                   const float* __restrict__ x,
                                                   short* __restrict__ Wfrag,
                                                   short* __restrict__ BfragX,
                                                   short* __restrict__ Sfrag) {
    __shared__ float xs[9216];
    __shared__ float Ss[1536];
    const int t = threadIdx.x;
    const int blk = blockIdx.x;

    if (blk < 24) {
        const int s = blk;
        const int o = t >> 3;             // 0..63
        const int k0 = (t & 7) << 3;      // one 8-chunk
        bf16x8 vd, v1;
        #pragma unroll
        for (int e = 0; e < 8; ++e) {
            const float2 wv = *(const float2*)(weight + ((size_t)((o * 64 + k0 + e) * 24 + s) << 1));
            vd[e] = f2bf(wv.x - wv.y);
            v1[e] = f2bf(wv.y);
        }
        const int lane_f = (o & 15) | (((k0 >> 3) & 3) << 4);
        const int sub = ((o >> 4) * 2 + (k0 >> 5)) * 512 + lane_f * 8;
        *(bf16x8*)&Wfrag[(size_t)s * 4096 + sub] = vd;          // p=0: Wd
        *(bf16x8*)&Wfrag[(size_t)(24 + s) * 4096 + sub] = v1;   // p=1: W1
    } else {
        const int b = blk - 24;
        const float4* xg = (const float4*)(x + (size_t)b * 9216);
        float4* x4 = (float4*)xs;
        for (int idx = t; idx < 2304; idx += 512) x4[idx] = xg[idx];
        __syncthreads();
        #pragma unroll
        for (int u = 0; u < 3; ++u) {
            const int idx = t + u * 512;
            const float* p = xs + idx * 6;
            Ss[idx] = ((p[0] + p[1]) + (p[2] + p[3])) + (p[4] + p[5]);
        }
        __syncthreads();
        // 1152 x-chunks (6 d-rows x 192) + 192 S-chunks
        for (int cid = t; cid < 1344; cid += 512) {
            if (cid < 1152) {
                const int d = cid / 192;
                const int kk = (cid - d * 192) * 8;
                bf16x8 v;
                #pragma unroll
                for (int e = 0; e < 8; ++e) v[e] = f2bf(xs[(kk + e) * 6 + d]);
                const int n = b * 6 + d;
                const int lane_f = (n & 15) | (((kk >> 3) & 3) << 4);
                *(bf16x8*)&BfragX[(size_t)((n >> 4) * 48 + (kk >> 5)) * 512 + lane_f * 8] = v;
            } else {
                const int kk = (cid - 1152) * 8;
                bf16x8 v;
                #pragma unroll
                for (int e = 0; e < 8; ++e) v[e] = f2bf(Ss[kk + e]);
                const int lane_f = (b & 15) | (((kk >> 3) & 3) << 4);
                *(bf16x8*)&Sfrag[(size_t)((b >> 4) * 48 + (kk >> 5)) * 512 + lane_f * 8] = v;
            }
        }
    }
}

// ------- fused GEMM: main (M=1536 N=384 K=1536) + per-block T (32m x 16b) -------
__global__ __launch_bounds__(256, 3) void gemm_kernel(const short* __restrict__ Wfrag,
                                                      const short* __restrict__ BfragX,
                                                      const short* __restrict__ Sfrag,
                                                      const float* __restrict__ bias,
                                                      const int* __restrict__ sp,
                                                      float* __restrict__ out) {
    __shared__ __align__(16) float RedM[4][64][16];   // 16 KB
    __shared__ __align__(16) float RedT[4][64][8];    //  8 KB

    const int tid = threadIdx.x;
    const int lane = tid & 63;
    const int w = tid >> 6;          // 0..3

    const int bx = (int)blockIdx.x;
    const int mt = bx % 48;
    const int nt = bx / 48;          // 0..11
    const int i  = mt >> 1;
    const int o0 = (mt & 1) * 32;
    const int n0 = nt * 32;
    const int bg = nt / 3;           // the single 16-b group this n-range touches

    const int jbase = w * 6;         // 4 waves x 6 j = 24
    int sidx[6];
    #pragma unroll
    for (int t_ = 0; t_ < 6; ++t_) sidx[t_] = sp[i * 24 + jbase + t_];

    const size_t abase0  = (size_t)(o0 >> 4) * 1024 + lane * 8;              // p=0 (Wd)
    const size_t a1base0 = (size_t)24 * 4096 + abase0;                       // p=1 (W1)
    const short* bbase = BfragX + (size_t)(n0 >> 4) * 24576 + (size_t)jbase * 1024 + lane * 8;
    const short* sbase = Sfrag  + (size_t)bg * 24576 + (size_t)jbase * 1024 + lane * 8;

    f32x4 acc[2][2] = {{{0.f,0.f,0.f,0.f},{0.f,0.f,0.f,0.f}},
                       {{0.f,0.f,0.f,0.f},{0.f,0.f,0.f,0.f}}};
    f32x4 accT[2] = {{0.f,0.f,0.f,0.f},{0.f,0.f,0.f,0.f}};
    bf16x8 rA[2][4], rB[2][4], rA1[2][4], rBs[2][2];

    // prefetch EVERYTHING for step t_: main A/B + T-term A1/S
#define LOADSTEP(t_, buf)                                                       \
    {                                                                           \
        const short* ap  = Wfrag + (size_t)sidx[t_] * 4096 + abase0;            \
        const short* a1p = Wfrag + (size_t)sidx[t_] * 4096 + a1base0;           \
        const short* bp  = bbase + (t_) * 1024;                                 \
        const short* spp = sbase + (t_) * 1024;                                 \
        _Pragma("unroll")                                                       \
        for (int f = 0; f < 4; ++f) {                                           \
            rA[buf][f]  = *(const bf16x8*)(ap + f * 512);                       \
            rB[buf][f]  = *(const bf16x8*)(bp + ((f >> 1) * 24576) + (f & 1) * 512); \
            rA1[buf][f] = *(const bf16x8*)(a1p + f * 512);                      \
        }                                                                       \
        rBs[buf][0] = *(const bf16x8*)spp;                                      \
        rBs[buf][1] = *(const bf16x8*)(spp + 512);                              \
    }

    LOADSTEP(0, 0)
    #pragma unroll
    for (int t_ = 0; t_ < 6; ++t_) {
        const int cur = t_ & 1;
        if (t_ < 5) LOADSTEP(t_ + 1, cur ^ 1)

        #pragma unroll
        for (int kc = 0; kc < 2; ++kc)
            #pragma unroll
            for (int mi = 0; mi < 2; ++mi)
                #pragma unroll
                for (int ni = 0; ni < 2; ++ni)
                    acc[mi][ni] = MFMA16(rA[cur][mi * 2 + kc], rB[cur][ni * 2 + kc], acc[mi][ni]);

        #pragma unroll
        for (int kc = 0; kc < 2; ++kc)
            #pragma unroll
            for (int mi = 0; mi < 2; ++mi)
                accT[mi] = MFMA16(rA1[cur][mi * 2 + kc], rBs[cur][kc], accT[mi]);
    }
#undef LOADSTEP

    #pragma unroll
    for (int mi = 0; mi < 2; ++mi) {
        #pragma unroll
        for (int ni = 0; ni < 2; ++ni)
            *(f32x4*)&RedM[w][lane][mi * 8 + ni * 4] = acc[mi][ni];
        *(f32x4*)&RedT[w][lane][mi * 4] = accT[mi];
    }
    __syncthreads();

    {
        const int l  = tid & 63;
        const int g  = tid >> 6;
        const int mi = g >> 1;
        const int ni = g & 1;
        const int fb = mi * 8 + ni * 4;
        f32x4 sum = *(const f32x4*)&RedM[0][l][fb];
        #pragma unroll
        for (int ww = 1; ww < 4; ++ww) sum += *(const f32x4*)&RedM[ww][l][fb];

        // C/D layout: col = lane&15, row = (lane>>4)*4 + r  [verified r2-r8]
        const int col = n0 + ni * 16 + (l & 15);
        const int b = col / 6;
        const int d = col - b * 6;
        const int bcol = b - bg * 16;              // 0..15 within this block's b-group
        const int lT = ((l >> 4) << 4) | bcol;     // lane holding (same row group, col=bcol)
        f32x4 ts = *(const f32x4*)&RedT[0][lT][mi * 4];
        #pragma unroll
        for (int ww = 1; ww < 4; ++ww) ts += *(const f32x4*)&RedT[ww][lT][mi * 4];

        const int rb = (l >> 4) * 4;
        const int obase = o0 + mi * 16 + rb;
        const f32x4 bv = *(const f32x4*)&bias[obase];
        #pragma unroll
        for (int r = 0; r < 4; ++r) {
            out[((size_t)(b * 24 + i)) * 384 + (obase + r) * 6 + d] = sum[r] + ts[r] + bv[r];
        }
    }
}

extern "C" void kernel_launch(void* const* d_in, const int* in_sizes, int n_in,
                              void* d_out, int out_size, void* d_ws, size_t ws_size,
                              hipStream_t stream) {
    const float* x      = (const float*)d_in[0];
    const float* weight = (const float*)d_in[1];
    const float* bias   = (const float*)d_in[2];
    const int*   sp     = (const int*)d_in[3];
    // d_in[4] = co_orbit: folded into the (d != c) factorization.

    short* Wfrag  = (short*)d_ws;                     // 2*24*4096 = 196608 bf16
    short* BfragX = Wfrag + 196608;                   // 384*1536  = 589824 bf16
    short* Sfrag  = BfragX + 589824;                  // 64*1536   =  98304 bf16

    prep_kernel<<<88, 512, 0, stream>>>(weight, x, Wfrag, BfragX, Sfrag);
    gemm_kernel<<<576, 256, 0, stream>>>(Wfrag, BfragX, Sfrag, bias, sp, (float*)d_out);
}